// Round 7
// baseline (321.539 us; speedup 1.0000x reference)
//
#include <hip/hip_runtime.h>

// (B,C,H,W) = (4,16,320,640), fp32 throughout.
constexpr int Bn = 4;
constexpr int Cn = 16;
constexpr int Hn = 320;
constexpr int Wn = 640;
constexpr int NCOL = Bn * Cn * Wn;   // 40960 vertical columns
constexpr int NROW = Bn * Cn * Hn;   // 20480 horizontal rows

// ---------------------------------------------------------------------------
// Vertical scan, both directions, FLOAT4-WIDE columns.
// Rounds 1-6 falsified the spill theory: spilling (VGPR=52/56) and zero-spill
// (VGPR=32, LDS-stash) designs ALL run ~72us with VALUBusy ~7%, HBM 22%,
// occupancy 32-65% (no effect). The invariant across all of them is the
// block footprint: 32 cols = 128 B useful per 2560 B memory row -> every
// 128 B chunk costs a full DRAM-row/sector activation; data path pinned at
// ~1.8 TB/s HBM. This version widens the footprint 4x:
//   thread owns 4 adjacent columns (float4); block = 32 segs x 32 tcols
//   = 128 columns -> 512 B contiguous per row per 32-lane group, 1/4 the
//   load instructions, 4x bytes per outstanding request. Grid = 320.
// Register plan: ~136 live floats at P2 peak. amdgpu_waves_per_eu(4,4)
// pins the allocator's occupancy TARGET at 4 waves/EU -> 128-VGPR budget
// (launch_bounds alone provably doesn't raise its choice; rounds 1-2).
// ~10 floats spill -> 48 B/thread -> 1.6 MB/XCD, L2-contained.
// Structure: P1 DOWN float4 scan (x,g0) -> b -> stitch(tid<32) -> b ->
// fixup d in regs; P2 UP float4 scan (re-read x [L3-hot], g1) -> b ->
// stitch -> b -> P3 u-fixup + single coalesced float4 store of max(d,u).
// Recurrence: y = g*y_prev + x*(1-g) == fma(g, y_prev - x, x); g:=0 at head.
// ---------------------------------------------------------------------------
constexpr int HS = 10;               // rows per segment (320 = 32*10)
constexpr int NS = 32;               // segments per column
constexpr int TC = 32;               // thread-cols (float4) per block
constexpr int CPB = TC * 4;          // 128 scalar columns per block
constexpr int GPW = Wn / CPB;        // 5 column-groups per image width
constexpr int W4 = Wn / 4;           // 160 float4s per row

#define REP10(M) M(0) M(1) M(2) M(3) M(4) M(5) M(6) M(7) M(8) M(9)
#define REP10R(M) M(9) M(8) M(7) M(6) M(5) M(4) M(3) M(2) M(1) M(0)

// componentwise helpers
#define SCAN4(gv, xv, yy, pp)                                         \
  yy.x = fmaf(gv.x, yy.x - xv.x, xv.x); pp.x *= gv.x;                 \
  yy.y = fmaf(gv.y, yy.y - xv.y, xv.y); pp.y *= gv.y;                 \
  yy.z = fmaf(gv.z, yy.z - xv.z, xv.z); pp.z *= gv.z;                 \
  yy.w = fmaf(gv.w, yy.w - xv.w, xv.w); pp.w *= gv.w;

__global__ __launch_bounds__(1024)
__attribute__((amdgpu_waves_per_eu(4, 4))) void vert_both(
    const float* __restrict__ x, const float* __restrict__ g0,
    const float* __restrict__ g1, float* __restrict__ vm) {
  __shared__ float4 As[NS][TC], Bs[NS][TC];          // 32 KB
  const int grp = blockIdx.x;              // 320 groups
  const int bc = grp / GPW;
  const int q0 = (grp % GPW) * TC;         // float4-column base
  const int s = threadIdx.x >> 5;          // segment 0..31
  const int tc = threadIdx.x & 31;         // thread-col 0..31
  const int base = bc * (Hn * W4) + (s * HS) * W4 + q0 + tc;  // float4 units
  const float4* x4 = (const float4*)x;
  const float4* g04 = (const float4*)g0;
  const float4* g14 = (const float4*)g1;
  float4* vm4 = (float4*)vm;

#define DECLD(i) float4 rd##i, pd##i;
  REP10(DECLD)
#undef DECLD

  // ---------------- P1: DOWN local scan (g0, rows ascending) ----------------
  {
    int off = base;
    float4 yy = make_float4(0.f, 0.f, 0.f, 0.f);
    float4 pp = make_float4(1.f, 1.f, 1.f, 1.f);
#define DSTEP(i)                                                      \
    {                                                                 \
      float4 xv = x4[off];                                            \
      float4 gv = g04[off];                                           \
      if (s == 0 && i == 0) gv = make_float4(0.f, 0.f, 0.f, 0.f);     \
      SCAN4(gv, xv, yy, pp)                                           \
      rd##i = yy;                                                     \
      pd##i = pp;                                                     \
      off += W4;                                                      \
    }
    REP10(DSTEP)
#undef DSTEP
    As[s][tc] = yy;
    Bs[s][tc] = pp;
  }
  __syncthreads();
  if (threadIdx.x < 32) {                  // DOWN stitch, 32 lanes x 4 cols
    const int t = threadIdx.x;
    float4 c = make_float4(0.f, 0.f, 0.f, 0.f);
#pragma unroll
    for (int ss = 0; ss < NS; ++ss) {
      float4 a = As[ss][t], b = Bs[ss][t];
      As[ss][t] = c;                       // carry-in for segment ss
      c.x = fmaf(b.x, c.x, a.x);
      c.y = fmaf(b.y, c.y, a.y);
      c.z = fmaf(b.z, c.z, a.z);
      c.w = fmaf(b.w, c.w, a.w);
    }
  }
  __syncthreads();

  // ---- fixup DOWN in regs (rd becomes d; pd dies) ----
  {
    const float4 cd = As[s][tc];
#define FIXD(i)                                                       \
    rd##i.x = fmaf(pd##i.x, cd.x, rd##i.x);                           \
    rd##i.y = fmaf(pd##i.y, cd.y, rd##i.y);                           \
    rd##i.z = fmaf(pd##i.z, cd.z, rd##i.z);                           \
    rd##i.w = fmaf(pd##i.w, cd.w, rd##i.w);
    REP10(FIXD)
#undef FIXD
  }

  // ---------------- P2: UP local scan (g1, rows descending) ----------------
#define DECLU(i) float4 yu##i, pu##i;
  REP10(DECLU)
#undef DECLU
  {
    int off = base + (HS - 1) * W4;
    float4 yy = make_float4(0.f, 0.f, 0.f, 0.f);
    float4 pp = make_float4(1.f, 1.f, 1.f, 1.f);
#define USTEP(i)                                                      \
    {                                                                 \
      float4 xv = x4[off];                                            \
      float4 gv = g14[off];                                           \
      if (s == NS - 1 && i == HS - 1) gv = make_float4(0.f, 0.f, 0.f, 0.f); \
      SCAN4(gv, xv, yy, pp)                                           \
      yu##i = yy;                                                     \
      pu##i = pp;                                                     \
      off -= W4;                                                      \
    }
    REP10R(USTEP)
#undef USTEP
    As[s][tc] = yy;                        // own slot only; DOWN stitch done,
    Bs[s][tc] = pp;                        // own cd already read (prog order)
  }
  __syncthreads();
  if (threadIdx.x < 32) {                  // UP stitch (reverse)
    const int t = threadIdx.x;
    float4 c = make_float4(0.f, 0.f, 0.f, 0.f);
#pragma unroll
    for (int ss = NS - 1; ss >= 0; --ss) {
      float4 a = As[ss][t], b = Bs[ss][t];
      As[ss][t] = c;                       // carry-in from below
      c.x = fmaf(b.x, c.x, a.x);
      c.y = fmaf(b.y, c.y, a.y);
      c.z = fmaf(b.z, c.z, a.z);
      c.w = fmaf(b.w, c.w, a.w);
    }
  }
  __syncthreads();

  // ---------- P3: UP fixup + max with reg-resident DOWN + single store ----
  {
    const float4 cu = As[s][tc];
    int off = base;
#define FSTEP(i)                                                      \
    {                                                                 \
      float4 o;                                                       \
      o.x = fmaxf(rd##i.x, fmaf(pu##i.x, cu.x, yu##i.x));             \
      o.y = fmaxf(rd##i.y, fmaf(pu##i.y, cu.y, yu##i.y));             \
      o.z = fmaxf(rd##i.z, fmaf(pu##i.z, cu.z, yu##i.z));             \
      o.w = fmaxf(rd##i.w, fmaf(pu##i.w, cu.w, yu##i.w));             \
      vm4[off] = o;                                                   \
      off += W4;                                                      \
    }
    REP10(FSTEP)
#undef FSTEP
  }
}

// ---------------------------------------------------------------------------
// Horizontal + final: block = 256 threads = 4 waves, 4 consecutive rows.
// Stage x/g2/g3 into LDS with coalesced float4 loads; prefetch vm(=out) into
// registers at the same time. One wave per row does the lane-segmented scan
// (WSEG=10) from LDS with one 6-step shuffle scan of (A,B) per direction.
// Final: out = max(r_right, r_left, vm) — same lines this block read.
// ---------------------------------------------------------------------------
constexpr int WSEG = 10;                   // 64 lanes * 10 = 640

__global__ __launch_bounds__(256) void horiz_final(
    const float* __restrict__ x, const float* __restrict__ g2,
    const float* __restrict__ g3, const float* __restrict__ vm,
    float* __restrict__ out) {
  __shared__ float xs[4 * Wn], rrs[4 * Wn], rls[4 * Wn];   // 30 KB
  const int tid = threadIdx.x, wv = tid >> 6, l = tid & 63;
  const size_t rowbase = (size_t)blockIdx.x * 4 * Wn;      // 4 rows contiguous

  const float4* xg = (const float4*)(x + rowbase);
  const float4* g2g = (const float4*)(g2 + rowbase);
  const float4* g3g = (const float4*)(g3 + rowbase);
  const float4* vm4 = (const float4*)(vm + rowbase);
  float4* xsv = (float4*)xs;
  float4* rrv = (float4*)rrs;
  float4* rlv = (float4*)rls;

  // ---- stage (coalesced float4); vm prefetched into registers ----
  const int i0 = tid, i1 = tid + 256, i2 = tid + 512;      // i2 valid if tid<128
  float4 v0, v1, v2;
  xsv[i0] = xg[i0]; rrv[i0] = g2g[i0]; rlv[i0] = g3g[i0]; v0 = vm4[i0];
  xsv[i1] = xg[i1]; rrv[i1] = g2g[i1]; rlv[i1] = g3g[i1]; v1 = vm4[i1];
  if (i2 < Wn) { xsv[i2] = xg[i2]; rrv[i2] = g2g[i2]; rlv[i2] = g3g[i2]; v2 = vm4[i2]; }
  __syncthreads();

  const int rb = wv * Wn + l * WSEG;
  float xl[WSEG], gl[WSEG], yl[WSEG], pl[WSEG];
#pragma unroll
  for (int i = 0; i < WSEG; ++i) { xl[i] = xs[rb + i]; gl[i] = rrs[rb + i]; }

  // ---- forward (r_right) ----
  {
    float y = 0.0f, p = 1.0f;
#pragma unroll
    for (int i = 0; i < WSEG; ++i) {
      float bb = (l == 0 && i == 0) ? 0.0f : gl[i];
      y = fmaf(bb, y - xl[i], xl[i]);
      p *= bb;
      yl[i] = y; pl[i] = p;
    }
    float A = y, B = p;
#pragma unroll
    for (int off = 1; off < 64; off <<= 1) {
      float Au = __shfl_up(A, off);
      float Bu = __shfl_up(B, off);
      if (l >= off) { A = fmaf(B, Au, A); B *= Bu; }
    }
    float c = __shfl_up(A, 1);
    if (l == 0) c = 0.0f;
#pragma unroll
    for (int i = 0; i < WSEG; ++i) rrs[rb + i] = fmaf(pl[i], c, yl[i]);
  }

  // ---- backward (r_left) ----
#pragma unroll
  for (int i = 0; i < WSEG; ++i) gl[i] = rls[rb + i];
  {
    float y = 0.0f, p = 1.0f;
#pragma unroll
    for (int i = WSEG - 1; i >= 0; --i) {
      float bb = (l == 63 && i == WSEG - 1) ? 0.0f : gl[i];
      y = fmaf(bb, y - xl[i], xl[i]);
      p *= bb;
      yl[i] = y; pl[i] = p;
    }
    float A = y, B = p;
#pragma unroll
    for (int off = 1; off < 64; off <<= 1) {
      float Ad = __shfl_down(A, off);
      float Bd = __shfl_down(B, off);
      if (l + off < 64) { A = fmaf(B, Ad, A); B *= Bd; }
    }
    float c = __shfl_down(A, 1);
    if (l == 63) c = 0.0f;
#pragma unroll
    for (int i = 0; i < WSEG; ++i) rls[rb + i] = fmaf(pl[i], c, yl[i]);
  }
  __syncthreads();

  // ---- fused final max + store (coalesced float4) ----
  float4* o4 = (float4*)(out + rowbase);
  {
    float4 a = rrv[i0], b = rlv[i0];
    float4 o;
    o.x = fmaxf(fmaxf(a.x, b.x), v0.x);
    o.y = fmaxf(fmaxf(a.y, b.y), v0.y);
    o.z = fmaxf(fmaxf(a.z, b.z), v0.z);
    o.w = fmaxf(fmaxf(a.w, b.w), v0.w);
    o4[i0] = o;
  }
  {
    float4 a = rrv[i1], b = rlv[i1];
    float4 o;
    o.x = fmaxf(fmaxf(a.x, b.x), v1.x);
    o.y = fmaxf(fmaxf(a.y, b.y), v1.y);
    o.z = fmaxf(fmaxf(a.z, b.z), v1.z);
    o.w = fmaxf(fmaxf(a.w, b.w), v1.w);
    o4[i1] = o;
  }
  if (i2 < Wn) {
    float4 a = rrv[i2], b = rlv[i2];
    float4 o;
    o.x = fmaxf(fmaxf(a.x, b.x), v2.x);
    o.y = fmaxf(fmaxf(a.y, b.y), v2.y);
    o.z = fmaxf(fmaxf(a.z, b.z), v2.z);
    o.w = fmaxf(fmaxf(a.w, b.w), v2.w);
    o4[i2] = o;
  }
}

extern "C" void kernel_launch(void* const* d_in, const int* in_sizes, int n_in,
                              void* d_out, int out_size, void* d_ws,
                              size_t ws_size, hipStream_t stream) {
  const float* x = (const float*)d_in[0];
  const float* g0 = (const float*)d_in[1];
  const float* g1 = (const float*)d_in[2];
  const float* g2 = (const float*)d_in[3];
  const float* g3 = (const float*)d_in[4];
  float* out = (float*)d_out;

  // vert_both writes max(r_down, r_up) into out (single float4 store);
  // horiz_final consumes it (block-local lines) and overwrites with the
  // final 4-way max. No ws use.
  vert_both<<<NCOL / CPB, 1024, 0, stream>>>(x, g0, g1, out);
  horiz_final<<<NROW / 4, 256, 0, stream>>>(x, g2, g3, out, out);
}

// Round 8
// 273.177 us; speedup vs baseline: 1.1770x; 1.1770x over previous
//
#include <hip/hip_runtime.h>

// (B,C,H,W) = (4,16,320,640), fp32 throughout.
constexpr int Bn = 4;
constexpr int Cn = 16;
constexpr int Hn = 320;
constexpr int Wn = 640;
constexpr int NCOL = Bn * Cn * Wn;   // 40960 vertical columns
constexpr int NROW = Bn * Cn * Hn;   // 20480 horizontal rows

// ---------------------------------------------------------------------------
// Vertical scan, both directions, FLOAT2 columns, 64-VGPR-budget design.
// Facts from rounds 1-7: (a) the allocator never grants >64 VGPRs to this
// 1024-thread kernel (launch_bounds and waves_per_eu both ignored; round-7's
// forced attempt spilled ~100 MB to HBM, dur 128us); (b) all 128B-granularity
// variants (spilled or zero-spill, 32-65% occupancy) pin at ~72us with
// VALUBusy ~7%, HBM 1.8 TB/s -> suspected DRAM/sector granularity limit;
// (c) round-7's wide accesses sustained 2.37 TB/s even with 2x traffic.
//
// This version: 256B-contiguous wave loads with zero spill under 64 VGPRs.
//   Block = 1024 thr = 32 segments x 32 thread-cols (float2) = 64 scalar
//   cols; HS=10. Wave lanes 0-31 cover one row's 32 float2 = 256 B.
//   P1 DOWN scan: live rd/pd = 40 floats. stitch. fixup -> store d to vm.
//   P2 UP scan (reload x, L2/L3-hot): live yu/pu = 40 floats. stitch.
//   P3 RMW: read vm (own block's lines, L2-hot), max with u, store.
//   Peak live ~52 incl temps -> fits 64 VGPRs at ANY occupancy target.
// The __syncthreads between the vm store (P1) and vm load (P3) is a memory
// clobber: compiler must reload (keeps rd/pd dead through P2) and vmcnt(0)
// +barrier guarantees same-thread visibility through L2.
// Recurrence: y = g*y_prev + x*(1-g) == fma(g, y_prev - x, x); g:=0 at head.
// ---------------------------------------------------------------------------
constexpr int HS = 10;               // rows per segment (320 = 32*10)
constexpr int NS = 32;               // segments per column
constexpr int TC = 32;               // thread-cols (float2) per block
constexpr int CPB = TC * 2;          // 64 scalar columns per block
constexpr int GPW = Wn / CPB;        // 10 column-groups per image width
constexpr int W2 = Wn / 2;           // 320 float2s per row

#define REP10(M) M(0) M(1) M(2) M(3) M(4) M(5) M(6) M(7) M(8) M(9)
#define REP10R(M) M(9) M(8) M(7) M(6) M(5) M(4) M(3) M(2) M(1) M(0)

__global__ __launch_bounds__(1024) void vert_both(
    const float* __restrict__ x, const float* __restrict__ g0,
    const float* __restrict__ g1, float* __restrict__ vm) {
  __shared__ float2 As[NS][TC], Bs[NS][TC];          // 16 KB
  const int grp = blockIdx.x;              // 640 groups
  const int bc = grp / GPW;
  const int q0 = (grp % GPW) * TC;         // float2-column base
  const int s = threadIdx.x >> 5;          // segment 0..31
  const int tc = threadIdx.x & 31;         // thread-col 0..31
  const int base = bc * (Hn * W2) + (s * HS) * W2 + q0 + tc;  // float2 units
  const float2* x2 = (const float2*)x;
  const float2* g02 = (const float2*)g0;
  const float2* g12 = (const float2*)g1;
  float2* vm2 = (float2*)vm;

  // ---------------- P1: DOWN local scan (g0, rows ascending) ----------------
#define DECLD(i) float2 rd##i, pd##i;
  REP10(DECLD)
#undef DECLD
  {
    int off = base;
    float2 yy = make_float2(0.f, 0.f);
    float2 pp = make_float2(1.f, 1.f);
#define DSTEP(i)                                                      \
    {                                                                 \
      float2 xv = x2[off];                                            \
      float2 gv = g02[off];                                           \
      if (s == 0 && i == 0) gv = make_float2(0.f, 0.f);               \
      yy.x = fmaf(gv.x, yy.x - xv.x, xv.x); pp.x *= gv.x;             \
      yy.y = fmaf(gv.y, yy.y - xv.y, xv.y); pp.y *= gv.y;             \
      rd##i = yy;                                                     \
      pd##i = pp;                                                     \
      off += W2;                                                      \
    }
    REP10(DSTEP)
#undef DSTEP
    As[s][tc] = yy;
    Bs[s][tc] = pp;
  }
  __syncthreads();
  if (threadIdx.x < 32) {                  // DOWN stitch
    const int t = threadIdx.x;
    float2 c = make_float2(0.f, 0.f);
#pragma unroll
    for (int ss = 0; ss < NS; ++ss) {
      float2 a = As[ss][t], b = Bs[ss][t];
      As[ss][t] = c;                       // carry-in for segment ss
      c.x = fmaf(b.x, c.x, a.x);
      c.y = fmaf(b.y, c.y, a.y);
    }
  }
  __syncthreads();

  // ---- fixup DOWN + store d to vm (rd/pd die here; L2 keeps the lines) ----
  {
    const float2 cd = As[s][tc];
    int off = base;
#define FSTORE(i)                                                     \
    {                                                                 \
      float2 d;                                                       \
      d.x = fmaf(pd##i.x, cd.x, rd##i.x);                             \
      d.y = fmaf(pd##i.y, cd.y, rd##i.y);                             \
      vm2[off] = d;                                                   \
      off += W2;                                                      \
    }
    REP10(FSTORE)
#undef FSTORE
  }

  // ---------------- P2: UP local scan (g1, rows descending) ----------------
#define DECLU(i) float2 yu##i, pu##i;
  REP10(DECLU)
#undef DECLU
  {
    int off = base + (HS - 1) * W2;
    float2 yy = make_float2(0.f, 0.f);
    float2 pp = make_float2(1.f, 1.f);
#define USTEP(i)                                                      \
    {                                                                 \
      float2 xv = x2[off];                                            \
      float2 gv = g12[off];                                           \
      if (s == NS - 1 && i == HS - 1) gv = make_float2(0.f, 0.f);     \
      yy.x = fmaf(gv.x, yy.x - xv.x, xv.x); pp.x *= gv.x;             \
      yy.y = fmaf(gv.y, yy.y - xv.y, xv.y); pp.y *= gv.y;             \
      yu##i = yy;                                                     \
      pu##i = pp;                                                     \
      off -= W2;                                                      \
    }
    REP10R(USTEP)
#undef USTEP
    As[s][tc] = yy;                        // own slot; own cd already read
    Bs[s][tc] = pp;
  }
  __syncthreads();                         // also drains P1's vm stores
  if (threadIdx.x < 32) {                  // UP stitch (reverse)
    const int t = threadIdx.x;
    float2 c = make_float2(0.f, 0.f);
#pragma unroll
    for (int ss = NS - 1; ss >= 0; --ss) {
      float2 a = As[ss][t], b = Bs[ss][t];
      As[ss][t] = c;                       // carry-in from below
      c.x = fmaf(b.x, c.x, a.x);
      c.y = fmaf(b.y, c.y, a.y);
    }
  }
  __syncthreads();

  // ------- P3: UP fixup + RMW max with vm (own lines, L2-hot) -------
  {
    const float2 cu = As[s][tc];
    int off = base;
#define RSTEP(i)                                                      \
    {                                                                 \
      float2 dv = vm2[off];                                           \
      float2 o;                                                       \
      o.x = fmaxf(dv.x, fmaf(pu##i.x, cu.x, yu##i.x));                \
      o.y = fmaxf(dv.y, fmaf(pu##i.y, cu.y, yu##i.y));                \
      vm2[off] = o;                                                   \
      off += W2;                                                      \
    }
    REP10(RSTEP)
#undef RSTEP
  }
}

// ---------------------------------------------------------------------------
// Horizontal + final: block = 256 threads = 4 waves, 4 consecutive rows.
// Stage x/g2/g3 into LDS with coalesced float4 loads; prefetch vm(=out) into
// registers at the same time. One wave per row does the lane-segmented scan
// (WSEG=10) from LDS with one 6-step shuffle scan of (A,B) per direction.
// Final: out = max(r_right, r_left, vm) — same lines this block read.
// ---------------------------------------------------------------------------
constexpr int WSEG = 10;                   // 64 lanes * 10 = 640

__global__ __launch_bounds__(256) void horiz_final(
    const float* __restrict__ x, const float* __restrict__ g2,
    const float* __restrict__ g3, const float* __restrict__ vm,
    float* __restrict__ out) {
  __shared__ float xs[4 * Wn], rrs[4 * Wn], rls[4 * Wn];   // 30 KB
  const int tid = threadIdx.x, wv = tid >> 6, l = tid & 63;
  const size_t rowbase = (size_t)blockIdx.x * 4 * Wn;      // 4 rows contiguous

  const float4* xg = (const float4*)(x + rowbase);
  const float4* g2g = (const float4*)(g2 + rowbase);
  const float4* g3g = (const float4*)(g3 + rowbase);
  const float4* vm4 = (const float4*)(vm + rowbase);
  float4* xsv = (float4*)xs;
  float4* rrv = (float4*)rrs;
  float4* rlv = (float4*)rls;

  // ---- stage (coalesced float4); vm prefetched into registers ----
  const int i0 = tid, i1 = tid + 256, i2 = tid + 512;      // i2 valid if tid<128
  float4 v0, v1, v2;
  xsv[i0] = xg[i0]; rrv[i0] = g2g[i0]; rlv[i0] = g3g[i0]; v0 = vm4[i0];
  xsv[i1] = xg[i1]; rrv[i1] = g2g[i1]; rlv[i1] = g3g[i1]; v1 = vm4[i1];
  if (i2 < Wn) { xsv[i2] = xg[i2]; rrv[i2] = g2g[i2]; rlv[i2] = g3g[i2]; v2 = vm4[i2]; }
  __syncthreads();

  const int rb = wv * Wn + l * WSEG;
  float xl[WSEG], gl[WSEG], yl[WSEG], pl[WSEG];
#pragma unroll
  for (int i = 0; i < WSEG; ++i) { xl[i] = xs[rb + i]; gl[i] = rrs[rb + i]; }

  // ---- forward (r_right) ----
  {
    float y = 0.0f, p = 1.0f;
#pragma unroll
    for (int i = 0; i < WSEG; ++i) {
      float bb = (l == 0 && i == 0) ? 0.0f : gl[i];
      y = fmaf(bb, y - xl[i], xl[i]);
      p *= bb;
      yl[i] = y; pl[i] = p;
    }
    float A = y, B = p;
#pragma unroll
    for (int off = 1; off < 64; off <<= 1) {
      float Au = __shfl_up(A, off);
      float Bu = __shfl_up(B, off);
      if (l >= off) { A = fmaf(B, Au, A); B *= Bu; }
    }
    float c = __shfl_up(A, 1);
    if (l == 0) c = 0.0f;
#pragma unroll
    for (int i = 0; i < WSEG; ++i) rrs[rb + i] = fmaf(pl[i], c, yl[i]);
  }

  // ---- backward (r_left) ----
#pragma unroll
  for (int i = 0; i < WSEG; ++i) gl[i] = rls[rb + i];
  {
    float y = 0.0f, p = 1.0f;
#pragma unroll
    for (int i = WSEG - 1; i >= 0; --i) {
      float bb = (l == 63 && i == WSEG - 1) ? 0.0f : gl[i];
      y = fmaf(bb, y - xl[i], xl[i]);
      p *= bb;
      yl[i] = y; pl[i] = p;
    }
    float A = y, B = p;
#pragma unroll
    for (int off = 1; off < 64; off <<= 1) {
      float Ad = __shfl_down(A, off);
      float Bd = __shfl_down(B, off);
      if (l + off < 64) { A = fmaf(B, Ad, A); B *= Bd; }
    }
    float c = __shfl_down(A, 1);
    if (l == 63) c = 0.0f;
#pragma unroll
    for (int i = 0; i < WSEG; ++i) rls[rb + i] = fmaf(pl[i], c, yl[i]);
  }
  __syncthreads();

  // ---- fused final max + store (coalesced float4) ----
  float4* o4 = (float4*)(out + rowbase);
  {
    float4 a = rrv[i0], b = rlv[i0];
    float4 o;
    o.x = fmaxf(fmaxf(a.x, b.x), v0.x);
    o.y = fmaxf(fmaxf(a.y, b.y), v0.y);
    o.z = fmaxf(fmaxf(a.z, b.z), v0.z);
    o.w = fmaxf(fmaxf(a.w, b.w), v0.w);
    o4[i0] = o;
  }
  {
    float4 a = rrv[i1], b = rlv[i1];
    float4 o;
    o.x = fmaxf(fmaxf(a.x, b.x), v1.x);
    o.y = fmaxf(fmaxf(a.y, b.y), v1.y);
    o.z = fmaxf(fmaxf(a.z, b.z), v1.z);
    o.w = fmaxf(fmaxf(a.w, b.w), v1.w);
    o4[i1] = o;
  }
  if (i2 < Wn) {
    float4 a = rrv[i2], b = rlv[i2];
    float4 o;
    o.x = fmaxf(fmaxf(a.x, b.x), v2.x);
    o.y = fmaxf(fmaxf(a.y, b.y), v2.y);
    o.z = fmaxf(fmaxf(a.z, b.z), v2.z);
    o.w = fmaxf(fmaxf(a.w, b.w), v2.w);
    o4[i2] = o;
  }
}

extern "C" void kernel_launch(void* const* d_in, const int* in_sizes, int n_in,
                              void* d_out, int out_size, void* d_ws,
                              size_t ws_size, hipStream_t stream) {
  const float* x = (const float*)d_in[0];
  const float* g0 = (const float*)d_in[1];
  const float* g1 = (const float*)d_in[2];
  const float* g2 = (const float*)d_in[3];
  const float* g3 = (const float*)d_in[4];
  float* out = (float*)d_out;

  // vert_both writes max(r_down, r_up) into out (d staged through out with
  // an L2-hot RMW in P3); horiz_final consumes it (block-local lines) and
  // overwrites with the final 4-way max. No ws use.
  vert_both<<<NCOL / CPB, 1024, 0, stream>>>(x, g0, g1, out);
  horiz_final<<<NROW / 4, 256, 0, stream>>>(x, g2, g3, out, out);
}